// Round 1
// baseline (926.146 us; speedup 1.0000x reference)
//
#include <hip/hip_runtime.h>
#include <hip/hip_bf16.h>
#include <math.h>

typedef __hip_bfloat16 bf16;
typedef __attribute__((ext_vector_type(8))) short short8;
typedef __attribute__((ext_vector_type(4))) float f32x4;

// ---------------------------------------------------------------------------
// Weight prepack: fp32 [rows][sc] -> bf16 [rows][dc] (zero-pad cols >= sc)
// ---------------------------------------------------------------------------
struct Seg { const float* src; bf16* dst; int rows, sc, dc; };
struct Segs { Seg s[13]; };

__global__ __launch_bounds__(256) void prepack_kernel(Segs segs) {
  Seg sg = segs.s[blockIdx.y];
  long long total = (long long)sg.rows * sg.dc;
  for (long long idx = (long long)blockIdx.x * 256 + threadIdx.x; idx < total;
       idx += (long long)gridDim.x * 256) {
    int r = (int)(idx / sg.dc), c = (int)(idx % sg.dc);
    float v = (c < sg.sc) ? sg.src[(long long)r * sg.sc + c] : 0.f;
    sg.dst[idx] = __float2bfloat16(v);
  }
}

// ---------------------------------------------------------------------------
// im2col for 14x14/s14 patch conv: frames[128][3][224][224] f32 ->
// imcol[32768][608] bf16 (k >= 588 zero)
// ---------------------------------------------------------------------------
__global__ __launch_bounds__(256) void im2col_kernel(const float* __restrict__ frames,
                                                     bf16* __restrict__ out) {
  unsigned idx = blockIdx.x * 256u + threadIdx.x;  // < 32768*608 exactly
  unsigned k = idx % 608u;
  unsigned m = idx / 608u;
  float v = 0.f;
  if (k < 588u) {
    unsigned n = m >> 8;            // frame 0..127
    unsigned p = m & 255u;          // patch
    unsigned py = p >> 4, px = p & 15u;
    unsigned c = k / 196u, r = k % 196u;
    unsigned i = r / 14u, j = r % 14u;
    v = frames[((n * 3u + c) * 224u + (py * 14u + i)) * 224u + (px * 14u + j)];
  }
  out[idx] = __float2bfloat16(v);
}

// ---------------------------------------------------------------------------
// LayerNorm over D=768. Input either f32 or bf16; outputs f32 and/or bf16.
// Rows >= validRows are zero-filled (used to pad the latent-Q buffer to 128).
// ---------------------------------------------------------------------------
__global__ __launch_bounds__(256) void ln_kernel(const float* __restrict__ inF,
                                                 const bf16* __restrict__ inB,
                                                 const float* __restrict__ g,
                                                 const float* __restrict__ b,
                                                 float* __restrict__ outF,
                                                 bf16* __restrict__ outB,
                                                 int validRows) {
  int row = blockIdx.x;
  int tid = threadIdx.x;
  __shared__ float red[8];
  size_t base = (size_t)row * 768;
  if (row >= validRows) {
    for (int i = 0; i < 3; ++i) {
      int c = tid + i * 256;
      if (outB) outB[base + c] = __float2bfloat16(0.f);
      if (outF) outF[base + c] = 0.f;
    }
    return;
  }
  float x[3];
  for (int i = 0; i < 3; ++i) {
    int c = tid + i * 256;
    x[i] = inF ? inF[base + c] : __bfloat162float(inB[base + c]);
  }
  float s = x[0] + x[1] + x[2];
  float sq = x[0] * x[0] + x[1] * x[1] + x[2] * x[2];
  for (int off = 32; off; off >>= 1) {
    s += __shfl_down(s, off);
    sq += __shfl_down(sq, off);
  }
  int w = tid >> 6;
  if ((tid & 63) == 0) { red[w] = s; red[4 + w] = sq; }
  __syncthreads();
  if (tid == 0) {
    red[0] = red[0] + red[1] + red[2] + red[3];
    red[4] = red[4] + red[5] + red[6] + red[7];
  }
  __syncthreads();
  float mean = red[0] * (1.f / 768.f);
  float var = red[4] * (1.f / 768.f) - mean * mean;
  float rs = rsqrtf(var + 1e-5f);
  for (int i = 0; i < 3; ++i) {
    int c = tid + i * 256;
    float y = (x[i] - mean) * rs * g[c] + b[c];
    if (outF) outF[base + c] = y;
    if (outB) outB[base + c] = __float2bfloat16(y);
  }
}

// ---------------------------------------------------------------------------
// bf16 MFMA GEMM: out[M][N] = A[M][K] * Bw[N][K]^T + bias (+act) (+resid)
// 128x128 tile, BK=32, 4 waves (2x2), 16x16x32 MFMA, LDS rows padded to 40.
// M%128==0, N%128==0, K%32==0 assumed. act: 0=none, 1=gelu(tanh), 2=relu.
// ---------------------------------------------------------------------------
__global__ __launch_bounds__(256) void gemm_bf16(
    const bf16* __restrict__ A, const bf16* __restrict__ Bw,
    const float* __restrict__ bias, const float* __restrict__ resid,
    float* __restrict__ outF, bf16* __restrict__ outB,
    int M, int N, int K, int act) {
  __shared__ bf16 As[128 * 40];
  __shared__ bf16 Bs[128 * 40];
  int tid = threadIdx.x;
  int m0 = blockIdx.y * 128, n0 = blockIdx.x * 128;
  int lane = tid & 63, w = tid >> 6;
  int wr = w >> 1, wc = w & 1;
  int l15 = lane & 15, lq = lane >> 4;
  f32x4 acc[4][4] = {};

  for (int kt = 0; kt < K; kt += 32) {
    #pragma unroll
    for (int i = 0; i < 2; ++i) {
      int c = tid + i * 256;        // 0..511
      int row = c >> 2, kq = c & 3;
      uint4 va = *(const uint4*)(A + (size_t)(m0 + row) * K + kt + kq * 8);
      *(uint4*)(&As[row * 40 + kq * 8]) = va;
      uint4 vb = *(const uint4*)(Bw + (size_t)(n0 + row) * K + kt + kq * 8);
      *(uint4*)(&Bs[row * 40 + kq * 8]) = vb;
    }
    __syncthreads();
    short8 af[4], bfrag[4];
    #pragma unroll
    for (int mi = 0; mi < 4; ++mi)
      af[mi] = *(const short8*)(&As[(wr * 64 + mi * 16 + l15) * 40 + lq * 8]);
    #pragma unroll
    for (int ni = 0; ni < 4; ++ni)
      bfrag[ni] = *(const short8*)(&Bs[(wc * 64 + ni * 16 + l15) * 40 + lq * 8]);
    #pragma unroll
    for (int mi = 0; mi < 4; ++mi)
      #pragma unroll
      for (int ni = 0; ni < 4; ++ni)
        acc[mi][ni] = __builtin_amdgcn_mfma_f32_16x16x32_bf16(af[mi], bfrag[ni],
                                                              acc[mi][ni], 0, 0, 0);
    __syncthreads();
  }

  #pragma unroll
  for (int mi = 0; mi < 4; ++mi)
    #pragma unroll
    for (int ni = 0; ni < 4; ++ni) {
      int col = n0 + wc * 64 + ni * 16 + l15;
      float bv = bias ? bias[col] : 0.f;
      #pragma unroll
      for (int j = 0; j < 4; ++j) {
        int row = m0 + wr * 64 + mi * 16 + lq * 4 + j;
        float v = acc[mi][ni][j] + bv;
        if (act == 1) {
          float x = v;
          v = 0.5f * x * (1.f + tanhf(0.79788456080286535f * (x + 0.044715f * x * x * x)));
        } else if (act == 2) {
          v = fmaxf(v, 0.f);
        }
        size_t idx = (size_t)row * N + col;
        if (resid) v += resid[idx];
        if (outF) outF[idx] = v;
        if (outB) outB[idx] = __float2bfloat16(v);
      }
    }
}

// ---------------------------------------------------------------------------
// Flash attention, HD=96, stride 768, NH=8. Block = 4 waves, each wave owns
// 16 q-rows of a 64-row q-tile. K-chunks of 64. Q/K fragments read straight
// from global (contiguous in d); V transposed through padded LDS.
// Q rows: b*qRPB + qtile*64 (qRPB=0 => broadcast latents). O rows: b*oRPB+...
// ---------------------------------------------------------------------------
__global__ __launch_bounds__(256) void flash_kernel(
    const bf16* __restrict__ Q, const bf16* __restrict__ Kp,
    const bf16* __restrict__ V, bf16* __restrict__ O,
    int Lk, int qRPB, int kRPB, int oRPB) {
  const float scale = 0.10206207261596575f;  // 1/sqrt(96)
  __shared__ bf16 Vt[96 * 72];
  __shared__ bf16 Ps[4 * 16 * 72];
  int tid = threadIdx.x, lane = tid & 63, w = tid >> 6;
  int l15 = lane & 15, lq = lane >> 4;
  int b = blockIdx.z, h = blockIdx.y, qt = blockIdx.x;
  int qbase = b * qRPB + qt * 64 + w * 16;
  int kbase = b * kRPB;
  int obase = b * oRPB + qt * 64 + w * 16;
  int ch = h * 96;

  short8 aQ[3];
  #pragma unroll
  for (int kd = 0; kd < 3; ++kd)
    aQ[kd] = *(const short8*)(Q + (size_t)(qbase + l15) * 768 + ch + kd * 32 + lq * 8);

  f32x4 oacc[6] = {};
  float mrun[4] = {-1e30f, -1e30f, -1e30f, -1e30f};
  float lrun[4] = {0.f, 0.f, 0.f, 0.f};

  for (int kc = 0; kc < Lk; kc += 64) {
    // stage V chunk transposed: Vt[d][k], rows padded to 72
    for (int u = tid; u < 768; u += 256) {
      int kk = u / 12, dc = u % 12;
      short8 v = *(const short8*)(V + (size_t)(kbase + kc + kk) * 768 + ch + dc * 8);
      const bf16* pv = (const bf16*)&v;
      #pragma unroll
      for (int e = 0; e < 8; ++e) Vt[(dc * 8 + e) * 72 + kk] = pv[e];
    }
    __syncthreads();

    // S = Q K^T for this wave's 16 q-rows x 64 k
    f32x4 sacc[4] = {};
    #pragma unroll
    for (int ni = 0; ni < 4; ++ni)
      #pragma unroll
      for (int kd = 0; kd < 3; ++kd) {
        short8 bK = *(const short8*)(Kp + (size_t)(kbase + kc + ni * 16 + l15) * 768 +
                                     ch + kd * 32 + lq * 8);
        sacc[ni] = __builtin_amdgcn_mfma_f32_16x16x32_bf16(aQ[kd], bK, sacc[ni], 0, 0, 0);
      }
    #pragma unroll
    for (int ni = 0; ni < 4; ++ni)
      #pragma unroll
      for (int j = 0; j < 4; ++j) sacc[ni][j] *= scale;

    // online softmax per q-row j (16-lane groups hold the 64 k-cols)
    float al[4];
    #pragma unroll
    for (int j = 0; j < 4; ++j) {
      float mx = fmaxf(fmaxf(sacc[0][j], sacc[1][j]), fmaxf(sacc[2][j], sacc[3][j]));
      #pragma unroll
      for (int off = 1; off < 16; off <<= 1) mx = fmaxf(mx, __shfl_xor(mx, off));
      float mnew = fmaxf(mrun[j], mx);
      float alpha = __expf(mrun[j] - mnew);
      float rs = 0.f;
      #pragma unroll
      for (int ni = 0; ni < 4; ++ni) {
        float p = __expf(sacc[ni][j] - mnew);
        sacc[ni][j] = p;
        rs += p;
      }
      #pragma unroll
      for (int off = 1; off < 16; off <<= 1) rs += __shfl_xor(rs, off);
      lrun[j] = lrun[j] * alpha + rs;
      mrun[j] = mnew;
      al[j] = alpha;
    }

    // P -> LDS (wave-private), rescale O, then P x V
    #pragma unroll
    for (int ni = 0; ni < 4; ++ni)
      #pragma unroll
      for (int j = 0; j < 4; ++j)
        Ps[(w * 16 + lq * 4 + j) * 72 + ni * 16 + l15] = __float2bfloat16(sacc[ni][j]);
    #pragma unroll
    for (int t = 0; t < 6; ++t)
      #pragma unroll
      for (int j = 0; j < 4; ++j) oacc[t][j] *= al[j];
    short8 aP[2];
    #pragma unroll
    for (int ks = 0; ks < 2; ++ks)
      aP[ks] = *(const short8*)(&Ps[(w * 16 + l15) * 72 + ks * 32 + lq * 8]);
    #pragma unroll
    for (int t = 0; t < 6; ++t)
      #pragma unroll
      for (int ks = 0; ks < 2; ++ks) {
        short8 bV = *(const short8*)(&Vt[(t * 16 + l15) * 72 + ks * 32 + lq * 8]);
        oacc[t] = __builtin_amdgcn_mfma_f32_16x16x32_bf16(aP[ks], bV, oacc[t], 0, 0, 0);
      }
    __syncthreads();
  }

  #pragma unroll
  for (int t = 0; t < 6; ++t)
    #pragma unroll
    for (int j = 0; j < 4; ++j) {
      int row = obase + lq * 4 + j;
      int col = ch + t * 16 + l15;
      O[(size_t)row * 768 + col] = __float2bfloat16(oacc[t][j] / lrun[j]);
    }
}

// ---------------------------------------------------------------------------
extern "C" void kernel_launch(void* const* d_in, const int* in_sizes, int n_in,
                              void* d_out, int out_size, void* d_ws, size_t ws_size,
                              hipStream_t stream) {
  const float* frames = (const float*)d_in[0];
  const float* pe_w   = (const float*)d_in[1];
  const float* pe_b   = (const float*)d_in[2];
  const float* latents= (const float*)d_in[3];
  const float* ca_qw  = (const float*)d_in[4];  const float* ca_qb = (const float*)d_in[5];
  const float* ca_kw  = (const float*)d_in[6];  const float* ca_kb = (const float*)d_in[7];
  const float* ca_vw  = (const float*)d_in[8];  const float* ca_vb = (const float*)d_in[9];
  const float* ca_ow  = (const float*)d_in[10]; const float* ca_ob = (const float*)d_in[11];
  const float* nq_g   = (const float*)d_in[12]; const float* nq_b  = (const float*)d_in[13];
  const float* nkv_g  = (const float*)d_in[14]; const float* nkv_b = (const float*)d_in[15];
  const float* no_g   = (const float*)d_in[16]; const float* no_b  = (const float*)d_in[17];
  const float* m1_w   = (const float*)d_in[18]; const float* m1_b  = (const float*)d_in[19];
  const float* m2_w   = (const float*)d_in[20]; const float* m2_b  = (const float*)d_in[21];
  const float* sa_qw  = (const float*)d_in[22]; const float* sa_qb = (const float*)d_in[23];
  const float* sa_kw  = (const float*)d_in[24]; const float* sa_kb = (const float*)d_in[25];
  const float* sa_vw  = (const float*)d_in[26]; const float* sa_vb = (const float*)d_in[27];
  const float* sa_ow  = (const float*)d_in[28]; const float* sa_ob = (const float*)d_in[29];
  const float* f1_w   = (const float*)d_in[30]; const float* f1_b  = (const float*)d_in[31];
  const float* f2_w   = (const float*)d_in[32]; const float* f2_b  = (const float*)d_in[33];
  const float* n1_g   = (const float*)d_in[34]; const float* n1_b  = (const float*)d_in[35];
  const float* n2_g   = (const float*)d_in[36]; const float* n2_b  = (const float*)d_in[37];

  char* ws = (char*)d_ws;
  size_t off = 0;
  auto take = [&](size_t bytes) -> char* {
    char* p = ws + off;
    off += (bytes + 255) & ~(size_t)255;
    return p;
  };

  // persistent bf16 weights
  bf16* w_pe  = (bf16*)take((size_t)768 * 608 * 2);
  bf16* w_caq = (bf16*)take((size_t)768 * 768 * 2);
  bf16* w_cak = (bf16*)take((size_t)768 * 768 * 2);
  bf16* w_cav = (bf16*)take((size_t)768 * 768 * 2);
  bf16* w_cao = (bf16*)take((size_t)768 * 768 * 2);
  bf16* w_m1  = (bf16*)take((size_t)3072 * 768 * 2);
  bf16* w_m2  = (bf16*)take((size_t)768 * 3072 * 2);
  bf16* w_saq = (bf16*)take((size_t)768 * 768 * 2);
  bf16* w_sak = (bf16*)take((size_t)768 * 768 * 2);
  bf16* w_sav = (bf16*)take((size_t)768 * 768 * 2);
  bf16* w_sao = (bf16*)take((size_t)768 * 768 * 2);
  bf16* w_f1  = (bf16*)take((size_t)1536 * 768 * 2);
  bf16* w_f2  = (bf16*)take((size_t)768 * 1536 * 2);

  // q path (padded to 128 rows)
  bf16* q_ln = (bf16*)take((size_t)128 * 768 * 2);
  bf16* qh   = (bf16*)take((size_t)128 * 768 * 2);

  // big activations
  bf16* kv = (bf16*)take((size_t)32768 * 768 * 2);  // later LN'd in-place
  bf16* vh = (bf16*)take((size_t)32768 * 768 * 2);
  bf16* kh = (bf16*)take((size_t)32768 * 768 * 2);

  // union region: imcol (needed only until conv GEMM) vs stage-2/3 buffers
  char* region = take((size_t)32768 * 608 * 2);  // 39.85 MB
  bf16* imcol = (bf16*)region;
  size_t ro = 0;
  auto rtake = [&](size_t bytes) -> char* {
    char* p = region + ro;
    ro += (bytes + 255) & ~(size_t)255;
    return p;
  };
  bf16*  attn_o = (bf16*)rtake((size_t)1024 * 768 * 2);
  float* out_f  = (float*)rtake((size_t)1024 * 768 * 4);
  bf16*  h_b    = (bf16*)rtake((size_t)1024 * 768 * 2);
  bf16*  g_b    = (bf16*)rtake((size_t)1024 * 3072 * 2);
  float* tok_f  = (float*)rtake((size_t)1024 * 768 * 4);
  bf16*  tok_b  = (bf16*)rtake((size_t)1024 * 768 * 2);
  bf16*  xq     = (bf16*)rtake((size_t)1024 * 768 * 2);
  bf16*  xk     = (bf16*)rtake((size_t)1024 * 768 * 2);
  bf16*  xv     = (bf16*)rtake((size_t)1024 * 768 * 2);
  bf16*  sa_o   = (bf16*)rtake((size_t)1024 * 768 * 2);
  float* y_f    = (float*)rtake((size_t)1024 * 768 * 4);
  float* x1f    = (float*)rtake((size_t)1024 * 768 * 4);
  bf16*  x1b    = (bf16*)rtake((size_t)1024 * 768 * 2);
  bf16*  ff1    = (bf16*)rtake((size_t)1024 * 1536 * 2);
  float* z_f    = (float*)rtake((size_t)1024 * 768 * 4);
  (void)ws_size; (void)in_sizes; (void)n_in; (void)out_size;

  // 1) prepack all weights to bf16 (pe_w zero-padded K 588->608)
  Segs segs;
  segs.s[0]  = {pe_w,  w_pe,  768, 588, 608};
  segs.s[1]  = {ca_qw, w_caq, 768, 768, 768};
  segs.s[2]  = {ca_kw, w_cak, 768, 768, 768};
  segs.s[3]  = {ca_vw, w_cav, 768, 768, 768};
  segs.s[4]  = {ca_ow, w_cao, 768, 768, 768};
  segs.s[5]  = {m1_w,  w_m1,  3072, 768, 768};
  segs.s[6]  = {m2_w,  w_m2,  768, 3072, 3072};
  segs.s[7]  = {sa_qw, w_saq, 768, 768, 768};
  segs.s[8]  = {sa_kw, w_sak, 768, 768, 768};
  segs.s[9]  = {sa_vw, w_sav, 768, 768, 768};
  segs.s[10] = {f1_w,  w_f1,  1536, 768, 768};
  segs.s[11] = {f2_w,  w_f2,  768, 1536, 1536};
  segs.s[12] = {sa_ow, w_sao, 768, 768, 768};
  prepack_kernel<<<dim3(2304, 13), 256, 0, stream>>>(segs);

  // 2) LN(latents) -> q_ln bf16, rows 64..127 zeroed
  ln_kernel<<<128, 256, 0, stream>>>(latents, nullptr, nq_g, nq_b, nullptr, q_ln, 64);

  // 3) im2col
  im2col_kernel<<<77824, 256, 0, stream>>>(frames, imcol);

  // 4) patch-embed GEMM -> kv bf16 [32768][768]
  gemm_bf16<<<dim3(6, 256), 256, 0, stream>>>(imcol, w_pe, pe_b, nullptr, nullptr, kv,
                                              32768, 768, 608, 0);

  // 5) Q projection (M=128 padded) -> qh
  gemm_bf16<<<dim3(6, 1), 256, 0, stream>>>(q_ln, w_caq, ca_qb, nullptr, nullptr, qh,
                                            128, 768, 768, 0);

  // 6) V projection on RAW kv -> vh
  gemm_bf16<<<dim3(6, 256), 256, 0, stream>>>(kv, w_cav, ca_vb, nullptr, nullptr, vh,
                                              32768, 768, 768, 0);

  // 7) LN(kv) in-place (nkv)
  ln_kernel<<<32768, 256, 0, stream>>>(nullptr, kv, nkv_g, nkv_b, nullptr, kv, 32768);

  // 8) K projection on normalized kv -> kh
  gemm_bf16<<<dim3(6, 256), 256, 0, stream>>>(kv, w_cak, ca_kb, nullptr, nullptr, kh,
                                              32768, 768, 768, 0);

  // 9) cross-attention (Q broadcast: qRPB=0), Lk=2048 -> attn_o [1024][768]
  flash_kernel<<<dim3(1, 8, 16), 256, 0, stream>>>(qh, kh, vh, attn_o, 2048, 0, 2048, 64);

  // 10) O projection -> out_f (f32)
  gemm_bf16<<<dim3(6, 8), 256, 0, stream>>>(attn_o, w_cao, ca_ob, nullptr, out_f, nullptr,
                                            1024, 768, 768, 0);

  // 11) LN(out) -> h_b bf16
  ln_kernel<<<1024, 256, 0, stream>>>(out_f, nullptr, no_g, no_b, nullptr, h_b, 1024);

  // 12) MLP up + GELU -> g_b [1024][3072]
  gemm_bf16<<<dim3(24, 8), 256, 0, stream>>>(h_b, w_m1, m1_b, nullptr, nullptr, g_b,
                                             1024, 3072, 768, 1);

  // 13) MLP down + residual(out) -> tok (f32 + bf16)
  gemm_bf16<<<dim3(6, 8), 256, 0, stream>>>(g_b, w_m2, m2_b, out_f, tok_f, tok_b,
                                            1024, 768, 3072, 0);

  // 14-16) SA projections (no pre-LN)
  gemm_bf16<<<dim3(6, 8), 256, 0, stream>>>(tok_b, w_saq, sa_qb, nullptr, nullptr, xq,
                                            1024, 768, 768, 0);
  gemm_bf16<<<dim3(6, 8), 256, 0, stream>>>(tok_b, w_sak, sa_kb, nullptr, nullptr, xk,
                                            1024, 768, 768, 0);
  gemm_bf16<<<dim3(6, 8), 256, 0, stream>>>(tok_b, w_sav, sa_vb, nullptr, nullptr, xv,
                                            1024, 768, 768, 0);

  // 17) self-attention: 4 batches x 8 heads x 4 q-tiles, Lk=256
  flash_kernel<<<dim3(4, 8, 4), 256, 0, stream>>>(xq, xk, xv, sa_o, 256, 256, 256, 256);

  // 18) SA O-projection + residual(tok) -> y_f
  gemm_bf16<<<dim3(6, 8), 256, 0, stream>>>(sa_o, w_sao, sa_ob, tok_f, y_f, nullptr,
                                            1024, 768, 768, 0);

  // 19) LN n1 -> x1 (f32 + bf16)
  ln_kernel<<<1024, 256, 0, stream>>>(y_f, nullptr, n1_g, n1_b, x1f, x1b, 1024);

  // 20) FF up + ReLU -> ff1 [1024][1536]
  gemm_bf16<<<dim3(12, 8), 256, 0, stream>>>(x1b, w_f1, f1_b, nullptr, nullptr, ff1,
                                             1024, 1536, 768, 2);

  // 21) FF down + residual(x1) -> z_f
  gemm_bf16<<<dim3(6, 8), 256, 0, stream>>>(ff1, w_f2, f2_b, x1f, z_f, nullptr,
                                            1024, 768, 1536, 0);

  // 22) LN n2 -> d_out (f32)
  ln_kernel<<<1024, 256, 0, stream>>>(z_f, nullptr, n2_g, n2_b, (float*)d_out, nullptr, 1024);
}

// Round 2
// 761.653 us; speedup vs baseline: 1.2160x; 1.2160x over previous
//
#include <hip/hip_runtime.h>
#include <hip/hip_bf16.h>
#include <math.h>

typedef __hip_bfloat16 bf16;
typedef __attribute__((ext_vector_type(8))) short short8;
typedef __attribute__((ext_vector_type(4))) float f32x4;

__device__ __forceinline__ void gload16(const bf16* g, bf16* l) {
  __builtin_amdgcn_global_load_lds((const __attribute__((address_space(1))) void*)(g),
                                   (__attribute__((address_space(3))) void*)(l), 16, 0, 0);
}

// ---------------------------------------------------------------------------
// Weight prepack: fp32 [rows][sc] -> bf16 [rows][dc] (zero-pad cols >= sc)
// ---------------------------------------------------------------------------
struct Seg { const float* src; bf16* dst; int rows, sc, dc; };
struct Segs { Seg s[13]; };

__global__ __launch_bounds__(256) void prepack_kernel(Segs segs) {
  Seg sg = segs.s[blockIdx.y];
  long long total = (long long)sg.rows * sg.dc;
  for (long long idx = (long long)blockIdx.x * 256 + threadIdx.x; idx < total;
       idx += (long long)gridDim.x * 256) {
    int r = (int)(idx / sg.dc), c = (int)(idx % sg.dc);
    float v = (c < sg.sc) ? sg.src[(long long)r * sg.sc + c] : 0.f;
    sg.dst[idx] = __float2bfloat16(v);
  }
}

__global__ __launch_bounds__(256) void concat3_kernel(const float* __restrict__ a,
                                                      const float* __restrict__ b,
                                                      const float* __restrict__ c,
                                                      float* __restrict__ o) {
  int i = blockIdx.x * 256 + threadIdx.x;
  if (i < 2304)
    o[i] = i < 768 ? a[i] : (i < 1536 ? b[i - 768] : c[i - 1536]);
}

// ---------------------------------------------------------------------------
// im2col for 14x14/s14 patch conv
// ---------------------------------------------------------------------------
__global__ __launch_bounds__(256) void im2col_kernel(const float* __restrict__ frames,
                                                     bf16* __restrict__ out) {
  unsigned idx = blockIdx.x * 256u + threadIdx.x;  // < 32768*608 exactly
  unsigned k = idx % 608u;
  unsigned m = idx / 608u;
  float v = 0.f;
  if (k < 588u) {
    unsigned n = m >> 8;
    unsigned p = m & 255u;
    unsigned py = p >> 4, px = p & 15u;
    unsigned c = k / 196u, r = k % 196u;
    unsigned i = r / 14u, j = r % 14u;
    v = frames[((n * 3u + c) * 224u + (py * 14u + i)) * 224u + (px * 14u + j)];
  }
  out[idx] = __float2bfloat16(v);
}

// ---------------------------------------------------------------------------
// LayerNorm over D=768
// ---------------------------------------------------------------------------
__global__ __launch_bounds__(256) void ln_kernel(const float* __restrict__ inF,
                                                 const bf16* __restrict__ inB,
                                                 const float* __restrict__ g,
                                                 const float* __restrict__ b,
                                                 float* __restrict__ outF,
                                                 bf16* __restrict__ outB,
                                                 int validRows) {
  int row = blockIdx.x;
  int tid = threadIdx.x;
  __shared__ float red[8];
  size_t base = (size_t)row * 768;
  if (row >= validRows) {
    for (int i = 0; i < 3; ++i) {
      int c = tid + i * 256;
      if (outB) outB[base + c] = __float2bfloat16(0.f);
      if (outF) outF[base + c] = 0.f;
    }
    return;
  }
  float x[3];
  for (int i = 0; i < 3; ++i) {
    int c = tid + i * 256;
    x[i] = inF ? inF[base + c] : __bfloat162float(inB[base + c]);
  }
  float s = x[0] + x[1] + x[2];
  float sq = x[0] * x[0] + x[1] * x[1] + x[2] * x[2];
  for (int off = 32; off; off >>= 1) {
    s += __shfl_down(s, off);
    sq += __shfl_down(sq, off);
  }
  int w = tid >> 6;
  if ((tid & 63) == 0) { red[w] = s; red[4 + w] = sq; }
  __syncthreads();
  if (tid == 0) {
    red[0] = red[0] + red[1] + red[2] + red[3];
    red[4] = red[4] + red[5] + red[6] + red[7];
  }
  __syncthreads();
  float mean = red[0] * (1.f / 768.f);
  float var = red[4] * (1.f / 768.f) - mean * mean;
  float rs = rsqrtf(var + 1e-5f);
  for (int i = 0; i < 3; ++i) {
    int c = tid + i * 256;
    float y = (x[i] - mean) * rs * g[c] + b[c];
    if (outF) outF[base + c] = y;
    if (outB) outB[base + c] = __float2bfloat16(y);
  }
}

// ---------------------------------------------------------------------------
// bf16 MFMA GEMM, m97 structure: 128x128 tile, BK=32, linear LDS,
// global_load_lds width=16 staging. out = A[M][K] * Bw[N][K]^T + bias
// act: 0=none, 1=gelu(tanh), 2=relu. Optional f32 residual add.
// ---------------------------------------------------------------------------
__global__ __launch_bounds__(256) void gemm_bf16(
    const bf16* __restrict__ A, const bf16* __restrict__ Bw,
    const float* __restrict__ bias, const float* __restrict__ resid,
    float* __restrict__ outF, bf16* __restrict__ outB,
    int M, int N, int K, int act) {
  __shared__ bf16 As[128 * 32];
  __shared__ bf16 Bs[128 * 32];
  int tid = threadIdx.x;
  int m0 = blockIdx.y * 128, n0 = blockIdx.x * 128;
  int lane = tid & 63, w = tid >> 6;
  int wr = w >> 1, wc = w & 1;
  int l15 = lane & 15, lq = lane >> 4;
  int srow = lane >> 2, scol = (lane & 3) * 8;
  const bf16* Abase = A + (size_t)m0 * K;
  const bf16* Bbase = Bw + (size_t)n0 * K;
  f32x4 acc[4][4] = {};

  for (int kt = 0; kt < K; kt += 32) {
    #pragma unroll
    for (int i = 0; i < 2; ++i) {
      int seg = w * 2 + i;
      int row = seg * 16 + srow;
      gload16(Abase + (size_t)row * K + kt + scol, &As[seg * 512]);
      gload16(Bbase + (size_t)row * K + kt + scol, &Bs[seg * 512]);
    }
    __syncthreads();
    short8 af[4], bfrag[4];
    #pragma unroll
    for (int mi = 0; mi < 4; ++mi)
      af[mi] = *(const short8*)(&As[(wr * 64 + mi * 16 + l15) * 32 + lq * 8]);
    #pragma unroll
    for (int ni = 0; ni < 4; ++ni)
      bfrag[ni] = *(const short8*)(&Bs[(wc * 64 + ni * 16 + l15) * 32 + lq * 8]);
    #pragma unroll
    for (int mi = 0; mi < 4; ++mi)
      #pragma unroll
      for (int ni = 0; ni < 4; ++ni)
        acc[mi][ni] = __builtin_amdgcn_mfma_f32_16x16x32_bf16(af[mi], bfrag[ni],
                                                              acc[mi][ni], 0, 0, 0);
    __syncthreads();
  }

  #pragma unroll
  for (int mi = 0; mi < 4; ++mi)
    #pragma unroll
    for (int ni = 0; ni < 4; ++ni) {
      int col = n0 + wc * 64 + ni * 16 + l15;
      float bv = bias ? bias[col] : 0.f;
      #pragma unroll
      for (int j = 0; j < 4; ++j) {
        int row = m0 + wr * 64 + mi * 16 + lq * 4 + j;
        float v = acc[mi][ni][j] + bv;
        if (act == 1) {
          float x = v;
          v = 0.5f * x * (1.f + tanhf(0.79788456080286535f * (x + 0.044715f * x * x * x)));
        } else if (act == 2) {
          v = fmaxf(v, 0.f);
        }
        size_t idx = (size_t)row * N + col;
        if (resid) v += resid[idx];
        if (outF) outF[idx] = v;
        if (outB) outB[idx] = __float2bfloat16(v);
      }
    }
}

// ---------------------------------------------------------------------------
// Flash attention (non-split, used for SA). HD=96, NH=8, ld = Q/K/V row
// stride in elements; O row stride fixed 768.
// ---------------------------------------------------------------------------
__global__ __launch_bounds__(256) void flash_kernel(
    const bf16* __restrict__ Q, const bf16* __restrict__ Kp,
    const bf16* __restrict__ V, bf16* __restrict__ O,
    int Lk, int qRPB, int kRPB, int oRPB, int ld) {
  const float scale = 0.10206207261596575f;  // 1/sqrt(96)
  __shared__ bf16 Vt[96 * 72];
  __shared__ bf16 Ps[4 * 16 * 72];
  int tid = threadIdx.x, lane = tid & 63, w = tid >> 6;
  int l15 = lane & 15, lq = lane >> 4;
  int b = blockIdx.z, h = blockIdx.y, qt = blockIdx.x;
  int qbase = b * qRPB + qt * 64 + w * 16;
  int kbase = b * kRPB;
  int obase = b * oRPB + qt * 64 + w * 16;
  int ch = h * 96;

  short8 aQ[3];
  #pragma unroll
  for (int kd = 0; kd < 3; ++kd)
    aQ[kd] = *(const short8*)(Q + (size_t)(qbase + l15) * ld + ch + kd * 32 + lq * 8);

  f32x4 oacc[6] = {};
  float mrun[4] = {-1e30f, -1e30f, -1e30f, -1e30f};
  float lrun[4] = {0.f, 0.f, 0.f, 0.f};

  for (int kc = 0; kc < Lk; kc += 64) {
    for (int u = tid; u < 768; u += 256) {
      int kk = u / 12, dc = u % 12;
      short8 v = *(const short8*)(V + (size_t)(kbase + kc + kk) * ld + ch + dc * 8);
      const bf16* pv = (const bf16*)&v;
      #pragma unroll
      for (int e = 0; e < 8; ++e) Vt[(dc * 8 + e) * 72 + kk] = pv[e];
    }
    __syncthreads();

    f32x4 sacc[4] = {};
    #pragma unroll
    for (int ni = 0; ni < 4; ++ni)
      #pragma unroll
      for (int kd = 0; kd < 3; ++kd) {
        short8 bK = *(const short8*)(Kp + (size_t)(kbase + kc + ni * 16 + l15) * ld +
                                     ch + kd * 32 + lq * 8);
        sacc[ni] = __builtin_amdgcn_mfma_f32_16x16x32_bf16(aQ[kd], bK, sacc[ni], 0, 0, 0);
      }
    #pragma unroll
    for (int ni = 0; ni < 4; ++ni)
      #pragma unroll
      for (int j = 0; j < 4; ++j) sacc[ni][j] *= scale;

    float al[4];
    #pragma unroll
    for (int j = 0; j < 4; ++j) {
      float mx = fmaxf(fmaxf(sacc[0][j], sacc[1][j]), fmaxf(sacc[2][j], sacc[3][j]));
      #pragma unroll
      for (int off = 1; off < 16; off <<= 1) mx = fmaxf(mx, __shfl_xor(mx, off));
      float mnew = fmaxf(mrun[j], mx);
      float alpha = __expf(mrun[j] - mnew);
      float rs = 0.f;
      #pragma unroll
      for (int ni = 0; ni < 4; ++ni) {
        float p = __expf(sacc[ni][j] - mnew);
        sacc[ni][j] = p;
        rs += p;
      }
      #pragma unroll
      for (int off = 1; off < 16; off <<= 1) rs += __shfl_xor(rs, off);
      lrun[j] = lrun[j] * alpha + rs;
      mrun[j] = mnew;
      al[j] = alpha;
    }

    #pragma unroll
    for (int ni = 0; ni < 4; ++ni)
      #pragma unroll
      for (int j = 0; j < 4; ++j)
        Ps[(w * 16 + lq * 4 + j) * 72 + ni * 16 + l15] = __float2bfloat16(sacc[ni][j]);
    #pragma unroll
    for (int t = 0; t < 6; ++t)
      #pragma unroll
      for (int j = 0; j < 4; ++j) oacc[t][j] *= al[j];
    short8 aP[2];
    #pragma unroll
    for (int ks = 0; ks < 2; ++ks)
      aP[ks] = *(const short8*)(&Ps[(w * 16 + l15) * 72 + ks * 32 + lq * 8]);
    #pragma unroll
    for (int t = 0; t < 6; ++t)
      #pragma unroll
      for (int ks = 0; ks < 2; ++ks) {
        short8 bV = *(const short8*)(&Vt[(t * 16 + l15) * 72 + ks * 32 + lq * 8]);
        oacc[t] = __builtin_amdgcn_mfma_f32_16x16x32_bf16(aP[ks], bV, oacc[t], 0, 0, 0);
      }
    __syncthreads();
  }

  #pragma unroll
  for (int t = 0; t < 6; ++t)
    #pragma unroll
    for (int j = 0; j < 4; ++j) {
      int row = obase + lq * 4 + j;
      int col = ch + t * 16 + l15;
      O[(size_t)row * 768 + col] = __float2bfloat16(oacc[t][j] / lrun[j]);
    }
}

// ---------------------------------------------------------------------------
// Split-K flash for cross-attention (broadcast latent Q, 64 rows/batch).
// grid = (nsplit, 8 heads, 16 batches). Writes unnormalized partial O (f32)
// plus per-(split,b,h,q) running max m and denom l.
// ---------------------------------------------------------------------------
__global__ __launch_bounds__(256) void flash_split_kernel(
    const bf16* __restrict__ Q, const bf16* __restrict__ Kp,
    const bf16* __restrict__ V, float* __restrict__ Opart,
    float* __restrict__ Mpart, float* __restrict__ Lpart,
    int splitLen, int kRPB) {
  const float scale = 0.10206207261596575f;
  __shared__ bf16 Vt[96 * 72];
  __shared__ bf16 Ps[4 * 16 * 72];
  int tid = threadIdx.x, lane = tid & 63, w = tid >> 6;
  int l15 = lane & 15, lq = lane >> 4;
  int s = blockIdx.x, h = blockIdx.y, b = blockIdx.z;
  int kbase = b * kRPB + s * splitLen;
  int ch = h * 96;

  short8 aQ[3];
  #pragma unroll
  for (int kd = 0; kd < 3; ++kd)
    aQ[kd] = *(const short8*)(Q + (size_t)(w * 16 + l15) * 768 + ch + kd * 32 + lq * 8);

  f32x4 oacc[6] = {};
  float mrun[4] = {-1e30f, -1e30f, -1e30f, -1e30f};
  float lrun[4] = {0.f, 0.f, 0.f, 0.f};

  for (int kc = 0; kc < splitLen; kc += 64) {
    for (int u = tid; u < 768; u += 256) {
      int kk = u / 12, dc = u % 12;
      short8 v = *(const short8*)(V + (size_t)(kbase + kc + kk) * 768 + ch + dc * 8);
      const bf16* pv = (const bf16*)&v;
      #pragma unroll
      for (int e = 0; e < 8; ++e) Vt[(dc * 8 + e) * 72 + kk] = pv[e];
    }
    __syncthreads();

    f32x4 sacc[4] = {};
    #pragma unroll
    for (int ni = 0; ni < 4; ++ni)
      #pragma unroll
      for (int kd = 0; kd < 3; ++kd) {
        short8 bK = *(const short8*)(Kp + (size_t)(kbase + kc + ni * 16 + l15) * 768 +
                                     ch + kd * 32 + lq * 8);
        sacc[ni] = __builtin_amdgcn_mfma_f32_16x16x32_bf16(aQ[kd], bK, sacc[ni], 0, 0, 0);
      }
    #pragma unroll
    for (int ni = 0; ni < 4; ++ni)
      #pragma unroll
      for (int j = 0; j < 4; ++j) sacc[ni][j] *= scale;

    float al[4];
    #pragma unroll
    for (int j = 0; j < 4; ++j) {
      float mx = fmaxf(fmaxf(sacc[0][j], sacc[1][j]), fmaxf(sacc[2][j], sacc[3][j]));
      #pragma unroll
      for (int off = 1; off < 16; off <<= 1) mx = fmaxf(mx, __shfl_xor(mx, off));
      float mnew = fmaxf(mrun[j], mx);
      float alpha = __expf(mrun[j] - mnew);
      float rs = 0.f;
      #pragma unroll
      for (int ni = 0; ni < 4; ++ni) {
        float p = __expf(sacc[ni][j] - mnew);
        sacc[ni][j] = p;
        rs += p;
      }
      #pragma unroll
      for (int off = 1; off < 16; off <<= 1) rs += __shfl_xor(rs, off);
      lrun[j] = lrun[j] * alpha + rs;
      mrun[j] = mnew;
      al[j] = alpha;
    }

    #pragma unroll
    for (int ni = 0; ni < 4; ++ni)
      #pragma unroll
      for (int j = 0; j < 4; ++j)
        Ps[(w * 16 + lq * 4 + j) * 72 + ni * 16 + l15] = __float2bfloat16(sacc[ni][j]);
    #pragma unroll
    for (int t = 0; t < 6; ++t)
      #pragma unroll
      for (int j = 0; j < 4; ++j) oacc[t][j] *= al[j];
    short8 aP[2];
    #pragma unroll
    for (int ks = 0; ks < 2; ++ks)
      aP[ks] = *(const short8*)(&Ps[(w * 16 + l15) * 72 + ks * 32 + lq * 8]);
    #pragma unroll
    for (int t = 0; t < 6; ++t)
      #pragma unroll
      for (int ks = 0; ks < 2; ++ks) {
        short8 bV = *(const short8*)(&Vt[(t * 16 + l15) * 72 + ks * 32 + lq * 8]);
        oacc[t] = __builtin_amdgcn_mfma_f32_16x16x32_bf16(aP[ks], bV, oacc[t], 0, 0, 0);
      }
    __syncthreads();
  }

  int orow = b * 64 + w * 16;
  #pragma unroll
  for (int t = 0; t < 6; ++t)
    #pragma unroll
    for (int j = 0; j < 4; ++j)
      Opart[(size_t)(s * 1024 + orow + lq * 4 + j) * 768 + ch + t * 16 + l15] = oacc[t][j];
  if (l15 == 0) {
    #pragma unroll
    for (int j = 0; j < 4; ++j) {
      int qq = w * 16 + lq * 4 + j;
      int mi = ((s * 16 + b) * 8 + h) * 64 + qq;
      Mpart[mi] = mrun[j];
      Lpart[mi] = lrun[j];
    }
  }
}

__global__ __launch_bounds__(256) void flash_merge_kernel(
    const float* __restrict__ Opart, const float* __restrict__ Mpart,
    const float* __restrict__ Lpart, bf16* __restrict__ O, int nsplit) {
  int row = blockIdx.x;   // b*64+q
  int tid = threadIdx.x;
  int c0 = tid * 3;
  int b = row >> 6, q = row & 63;
  int h = c0 / 96;
  float m = -1e30f;
  for (int s = 0; s < nsplit; ++s)
    m = fmaxf(m, Mpart[((s * 16 + b) * 8 + h) * 64 + q]);
  float l = 0.f, o0 = 0.f, o1 = 0.f, o2 = 0.f;
  for (int s = 0; s < nsplit; ++s) {
    int mi = ((s * 16 + b) * 8 + h) * 64 + q;
    float ws = __expf(Mpart[mi] - m);
    l += ws * Lpart[mi];
    const float* op = Opart + (size_t)(s * 1024 + row) * 768 + c0;
    o0 += ws * op[0]; o1 += ws * op[1]; o2 += ws * op[2];
  }
  float inv = 1.f / l;
  size_t ob = (size_t)row * 768 + c0;
  O[ob]     = __float2bfloat16(o0 * inv);
  O[ob + 1] = __float2bfloat16(o1 * inv);
  O[ob + 2] = __float2bfloat16(o2 * inv);
}

// ---------------------------------------------------------------------------
extern "C" void kernel_launch(void* const* d_in, const int* in_sizes, int n_in,
                              void* d_out, int out_size, void* d_ws, size_t ws_size,
                              hipStream_t stream) {
  const float* frames = (const float*)d_in[0];
  const float* pe_w   = (const float*)d_in[1];
  const float* pe_b   = (const float*)d_in[2];
  const float* latents= (const float*)d_in[3];
  const float* ca_qw  = (const float*)d_in[4];  const float* ca_qb = (const float*)d_in[5];
  const float* ca_kw  = (const float*)d_in[6];  const float* ca_kb = (const float*)d_in[7];
  const float* ca_vw  = (const float*)d_in[8];  const float* ca_vb = (const float*)d_in[9];
  const float* ca_ow  = (const float*)d_in[10]; const float* ca_ob = (const float*)d_in[11];
  const float* nq_g   = (const float*)d_in[12]; const float* nq_b  = (const float*)d_in[13];
  const float* nkv_g  = (const float*)d_in[14]; const float* nkv_b = (const float*)d_in[15];
  const float* no_g   = (const float*)d_in[16]; const float* no_b  = (const float*)d_in[17];
  const float* m1_w   = (const float*)d_in[18]; const float* m1_b  = (const float*)d_in[19];
  const float* m2_w   = (const float*)d_in[20]; const float* m2_b  = (const float*)d_in[21];
  const float* sa_qw  = (const float*)d_in[22]; const float* sa_qb = (const float*)d_in[23];
  const float* sa_kw  = (const float*)d_in[24]; const float* sa_kb = (const float*)d_in[25];
  const float* sa_vw  = (const float*)d_in[26]; const float* sa_vb = (const float*)d_in[27];
  const float* sa_ow  = (const float*)d_in[28]; const float* sa_ob = (const float*)d_in[29];
  const float* f1_w   = (const float*)d_in[30]; const float* f1_b  = (const float*)d_in[31];
  const float* f2_w   = (const float*)d_in[32]; const float* f2_b  = (const float*)d_in[33];
  const float* n1_g   = (const float*)d_in[34]; const float* n1_b  = (const float*)d_in[35];
  const float* n2_g   = (const float*)d_in[36]; const float* n2_b  = (const float*)d_in[37];

  char* ws = (char*)d_ws;
  size_t off = 0;
  auto take = [&](size_t bytes) -> char* {
    char* p = ws + off;
    off += (bytes + 255) & ~(size_t)255;
    return p;
  };

  // persistent bf16 weights (w_saq/w_sak/w_sav contiguous => one [2304][768])
  bf16* w_pe  = (bf16*)take((size_t)768 * 608 * 2);
  bf16* w_caq = (bf16*)take((size_t)768 * 768 * 2);
  bf16* w_cak = (bf16*)take((size_t)768 * 768 * 2);
  bf16* w_cav = (bf16*)take((size_t)768 * 768 * 2);
  bf16* w_cao = (bf16*)take((size_t)768 * 768 * 2);
  bf16* w_m1  = (bf16*)take((size_t)3072 * 768 * 2);
  bf16* w_m2  = (bf16*)take((size_t)768 * 3072 * 2);
  bf16* w_saq = (bf16*)take((size_t)768 * 768 * 2);
  bf16* w_sak = (bf16*)take((size_t)768 * 768 * 2);
  bf16* w_sav = (bf16*)take((size_t)768 * 768 * 2);
  bf16* w_sao = (bf16*)take((size_t)768 * 768 * 2);
  bf16* w_f1  = (bf16*)take((size_t)1536 * 768 * 2);
  bf16* w_f2  = (bf16*)take((size_t)768 * 1536 * 2);
  float* sab_cat = (float*)take((size_t)2304 * 4);

  bf16* q_ln = (bf16*)take((size_t)128 * 768 * 2);
  bf16* qh   = (bf16*)take((size_t)128 * 768 * 2);

  bf16* kv = (bf16*)take((size_t)32768 * 768 * 2);
  bf16* vh = (bf16*)take((size_t)32768 * 768 * 2);
  bf16* kh = (bf16*)take((size_t)32768 * 768 * 2);

  // union region: imcol (steps 3-4) / CA split partials (step 9) /
  // stage-2/3 activations (steps 10+). attn_o pinned at region end.
  const size_t REGION = (size_t)32768 * 608 * 2;  // 39,845,888
  char* region = take(REGION);
  bf16*  imcol = (bf16*)region;
  float* Opart = (float*)region;                          // 25,165,824 B
  float* Mpart = (float*)(region + 25165824);             //    262,144 B
  float* Lpart = (float*)(region + 25165824 + 262144);    //    262,144 B
  bf16*  attn_o = (bf16*)(region + REGION - (size_t)1024 * 768 * 2);
  size_t ro = 0;
  auto rtake = [&](size_t bytes) -> char* {
    char* p = region + ro;
    ro += (bytes + 255) & ~(size_t)255;
    return p;
  };
  float* out_f  = (float*)rtake((size_t)1024 * 768 * 4);
  bf16*  h_b    = (bf16*)rtake((size_t)1024 * 768 * 2);
  bf16*  g_b    = (bf16*)rtake((size_t)1024 * 3072 * 2);
  float* tok_f  = (float*)rtake((size_t)1024 * 768 * 4);
  bf16*  tok_b  = (bf16*)rtake((size_t)1024 * 768 * 2);
  bf16*  xqkv   = (bf16*)rtake((size_t)1024 * 2304 * 2);
  bf16*  sa_o   = (bf16*)rtake((size_t)1024 * 768 * 2);
  float* y_f    = (float*)rtake((size_t)1024 * 768 * 4);
  float* x1f    = (float*)rtake((size_t)1024 * 768 * 4);
  bf16*  x1b    = (bf16*)rtake((size_t)1024 * 768 * 2);
  bf16*  ff1    = (bf16*)rtake((size_t)1024 * 1536 * 2);
  float* z_f    = (float*)rtake((size_t)1024 * 768 * 4);
  (void)ws_size; (void)in_sizes; (void)n_in; (void)out_size;

  // 1) prepack weights to bf16
  Segs segs;
  segs.s[0]  = {pe_w,  w_pe,  768, 588, 608};
  segs.s[1]  = {ca_qw, w_caq, 768, 768, 768};
  segs.s[2]  = {ca_kw, w_cak, 768, 768, 768};
  segs.s[3]  = {ca_vw, w_cav, 768, 768, 768};
  segs.s[4]  = {ca_ow, w_cao, 768, 768, 768};
  segs.s[5]  = {m1_w,  w_m1,  3072, 768, 768};
  segs.s[6]  = {m2_w,  w_m2,  768, 3072, 3072};
  segs.s[7]  = {sa_qw, w_saq, 768, 768, 768};
  segs.s[8]  = {sa_kw, w_sak, 768, 768, 768};
  segs.s[9]  = {sa_vw, w_sav, 768, 768, 768};
  segs.s[10] = {f1_w,  w_f1,  1536, 768, 768};
  segs.s[11] = {f2_w,  w_f2,  768, 1536, 1536};
  segs.s[12] = {sa_ow, w_sao, 768, 768, 768};
  prepack_kernel<<<dim3(2304, 13), 256, 0, stream>>>(segs);
  concat3_kernel<<<9, 256, 0, stream>>>(sa_qb, sa_kb, sa_vb, sab_cat);

  // 2) LN(latents) -> q_ln, rows 64..127 zeroed
  ln_kernel<<<128, 256, 0, stream>>>(latents, nullptr, nq_g, nq_b, nullptr, q_ln, 64);

  // 3) im2col
  im2col_kernel<<<77824, 256, 0, stream>>>(frames, imcol);

  // 4) patch-embed GEMM -> kv
  gemm_bf16<<<dim3(6, 256), 256, 0, stream>>>(imcol, w_pe, pe_b, nullptr, nullptr, kv,
                                              32768, 768, 608, 0);

  // 5) Q projection
  gemm_bf16<<<dim3(6, 1), 256, 0, stream>>>(q_ln, w_caq, ca_qb, nullptr, nullptr, qh,
                                            128, 768, 768, 0);

  // 6) V projection on raw kv
  gemm_bf16<<<dim3(6, 256), 256, 0, stream>>>(kv, w_cav, ca_vb, nullptr, nullptr, vh,
                                              32768, 768, 768, 0);

  // 7) LN(kv) in-place
  ln_kernel<<<32768, 256, 0, stream>>>(nullptr, kv, nkv_g, nkv_b, nullptr, kv, 32768);

  // 8) K projection
  gemm_bf16<<<dim3(6, 256), 256, 0, stream>>>(kv, w_cak, ca_kb, nullptr, nullptr, kh,
                                              32768, 768, 768, 0);

  // 9) cross-attention split-K: 8 splits x 8 heads x 16 batches
  flash_split_kernel<<<dim3(8, 8, 16), 256, 0, stream>>>(qh, kh, vh, Opart, Mpart, Lpart,
                                                         256, 2048);
  flash_merge_kernel<<<1024, 256, 0, stream>>>(Opart, Mpart, Lpart, attn_o, 8);

  // 10) O projection -> out_f
  gemm_bf16<<<dim3(6, 8), 256, 0, stream>>>(attn_o, w_cao, ca_ob, nullptr, out_f, nullptr,
                                            1024, 768, 768, 0);

  // 11) LN(out) -> h_b
  ln_kernel<<<1024, 256, 0, stream>>>(out_f, nullptr, no_g, no_b, nullptr, h_b, 1024);

  // 12) MLP up + GELU
  gemm_bf16<<<dim3(24, 8), 256, 0, stream>>>(h_b, w_m1, m1_b, nullptr, nullptr, g_b,
                                             1024, 3072, 768, 1);

  // 13) MLP down + residual
  gemm_bf16<<<dim3(6, 8), 256, 0, stream>>>(g_b, w_m2, m2_b, out_f, tok_f, tok_b,
                                            1024, 768, 3072, 0);

  // 14) merged SA Q/K/V projection -> xqkv [1024][2304]
  gemm_bf16<<<dim3(18, 8), 256, 0, stream>>>(tok_b, w_saq, sab_cat, nullptr, nullptr, xqkv,
                                             1024, 2304, 768, 0);

  // 15) self-attention
  flash_kernel<<<dim3(4, 8, 4), 256, 0, stream>>>(xqkv, xqkv + 768, xqkv + 1536, sa_o,
                                                  256, 256, 256, 256, 2304);

  // 16) SA O-projection + residual(tok)
  gemm_bf16<<<dim3(6, 8), 256, 0, stream>>>(sa_o, w_sao, sa_ob, tok_f, y_f, nullptr,
                                            1024, 768, 768, 0);

  // 17) LN n1
  ln_kernel<<<1024, 256, 0, stream>>>(y_f, nullptr, n1_g, n1_b, x1f, x1b, 1024);

  // 18) FF up + ReLU
  gemm_bf16<<<dim3(12, 8), 256, 0, stream>>>(x1b, w_f1, f1_b, nullptr, nullptr, ff1,
                                             1024, 1536, 768, 2);

  // 19) FF down + residual(x1)
  gemm_bf16<<<dim3(6, 8), 256, 0, stream>>>(ff1, w_f2, f2_b, x1f, z_f, nullptr,
                                            1024, 768, 1536, 0);

  // 20) LN n2 -> d_out
  ln_kernel<<<1024, 256, 0, stream>>>(z_f, nullptr, n2_g, n2_b, (float*)d_out, nullptr, 1024);
}